// Round 7
// baseline (610.779 us; speedup 1.0000x reference)
//
#include <hip/hip_runtime.h>
#include <math.h>

#define Bb 2
#define Ss 2048
#define Dd 1024
#define Hh 16
#define SP 2052   // padded seq rows per batch (2 zero rows each side)
#define NBSD 4194304  // Bb*Ss*Dd

typedef unsigned short u16;
typedef __bf16 bf16x8 __attribute__((ext_vector_type(8)));
typedef float f32x4 __attribute__((ext_vector_type(4)));
typedef unsigned short u16x8 __attribute__((ext_vector_type(8)));
typedef unsigned short u16x4 __attribute__((ext_vector_type(4)));

__device__ __forceinline__ u16 f2bf(float f) {
    union { float f; unsigned int u; } c; c.f = f;
    unsigned int u = c.u + 0x7FFFu + ((c.u >> 16) & 1u);
    return (u16)(u >> 16);
}

__device__ __forceinline__ void gload16(const void* g, void* l) {
    __builtin_amdgcn_global_load_lds(
        (const __attribute__((address_space(1))) void*)g,
        (__attribute__((address_space(3))) void*)l, 16, 0, 0);
}

// ---------------------------------------------------------------------------
// Weight prep: bf16 conversions + gate/scale folding.
// ---------------------------------------------------------------------------
__global__ void prep_weights(const float* __restrict__ Wq, const float* __restrict__ Wk,
                             const float* __restrict__ Wv, const float* __restrict__ Wo,
                             const float* __restrict__ w0, const float* __restrict__ b0,
                             const float* __restrict__ w1, const float* __restrict__ b1,
                             const float* __restrict__ gate,
                             u16* __restrict__ wqs, u16* __restrict__ wvb, u16* __restrict__ wob,
                             u16* __restrict__ Wc0, u16* __restrict__ Wc1, float* __restrict__ bc)
{
    int idx = blockIdx.x * 256 + threadIdx.x;
    const int NW = 1024 * 1024;
    if (idx < NW) { wqs[idx] = f2bf(Wq[idx] * 0.18033688011112042f); return; }
    idx -= NW;
    if (idx < NW) { wvb[idx] = f2bf(Wv[idx]); return; }
    idx -= NW;
    if (idx < NW) { wob[idx] = f2bf(Wo[idx]); return; }
    idx -= NW;
    if (idx < 512 * 3072) {
        int c = idx / 3072, rem = idx % 3072, t = rem >> 10, d = rem & 1023;
        float g = 1.f / (1.f + expf(-gate[c >> 6]));
        float v = g * w0[(c * 1024 + d) * 3 + t];
        if (t == 1) v += (1.f - g) * Wk[c * 1024 + d];
        Wc0[idx] = f2bf(v);
        return;
    }
    idx -= 512 * 3072;
    if (idx < 512 * 5120) {
        int c = idx / 5120, rem = idx % 5120, t = rem >> 10, d = rem & 1023;
        int cg = c + 512;
        float g = 1.f / (1.f + expf(-gate[cg >> 6]));
        float v = g * w1[(c * 1024 + d) * 5 + t];
        if (t == 2) v += (1.f - g) * Wk[cg * 1024 + d];
        Wc1[idx] = f2bf(v);
        return;
    }
    idx -= 512 * 5120;
    if (idx < 1024) {
        float g = 1.f / (1.f + expf(-gate[idx >> 6]));
        bc[idx] = g * (idx < 512 ? b0[idx] : b1[idx - 512]);
    }
}

// ---------------------------------------------------------------------------
// fp32 -> bf16 conversion into padded [B][SP][D] layout + Keff_f32 bias init.
// ---------------------------------------------------------------------------
__global__ void convert_inputs(const float* __restrict__ q, const float* __restrict__ k,
                               const float* __restrict__ v,
                               u16* __restrict__ qbf, u16* __restrict__ kbf, u16* __restrict__ vbf,
                               float* __restrict__ Kf32, const float* __restrict__ bc)
{
    int idx = blockIdx.x * 256 + threadIdx.x;
    const int per = (Bb * SP * Dd) / 8;    // 525312
    int which = idx / per;
    if (which >= 3) {
        int j = idx - 3 * per;             // Keff_f32 bias fill, float4 per thread
        if (j < NBSD / 4) {
            int e = j * 4, c = e & 1023;
            *(float4*)&Kf32[e] = *(const float4*)&bc[c];
        }
        return;
    }
    int e = (idx - which * per) * 8;
    const float* src = which == 0 ? q : which == 1 ? k : v;
    u16* dst = which == 0 ? qbf : which == 1 ? kbf : vbf;
    int rp = e >> 10, col = e & 1023;
    int b = rp / SP, r = rp - b * SP;
    u16x8 o;
    if (r >= 2 && r < SP - 2) {
        const float* s = &src[((size_t)b * Ss + (r - 2)) * Dd + col];
        float4 lo = *(const float4*)s, hi = *(const float4*)(s + 4);
        o[0] = f2bf(lo.x); o[1] = f2bf(lo.y); o[2] = f2bf(lo.z); o[3] = f2bf(lo.w);
        o[4] = f2bf(hi.x); o[5] = f2bf(hi.y); o[6] = f2bf(hi.z); o[7] = f2bf(hi.w);
    } else {
        #pragma unroll
        for (int j = 0; j < 8; j++) o[j] = 0;
    }
    *(u16x8*)&dst[e] = o;
}

// ---------------------------------------------------------------------------
// Mask compression: 32 int32 -> 1 bit word; per-row any-zero flag.
// ---------------------------------------------------------------------------
__global__ void mask_prep(const int* __restrict__ mask, unsigned int* __restrict__ bits,
                          int* __restrict__ rowflags)
{
    int row = blockIdx.x;
    int lane = threadIdx.x;
    const int* mp = mask + (size_t)row * Ss + lane * 32;
    unsigned int w = 0;
    #pragma unroll
    for (int j = 0; j < 32; j += 4) {
        int4 m4 = *(const int4*)&mp[j];
        if (m4.x != 0) w |= 1u << j;
        if (m4.y != 0) w |= 1u << (j + 1);
        if (m4.z != 0) w |= 1u << (j + 2);
        if (m4.w != 0) w |= 1u << (j + 3);
    }
    bits[(size_t)row * 64 + lane] = w;
    int anyz = __any(w != 0xFFFFFFFFu);
    if (lane == 0) rowflags[row] = anyz;
}

// ---------------------------------------------------------------------------
// Uniform split-K bf16 MFMA GEMM: every block does K=1024 (32 K-steps).
//   bid <256: Q-proj -> Qp(bf16);  <512: V-proj -> Vp(bf16)
//   <896: conv0 tap t=(bid-512)/128, atomicAdd into Keff_f32 (bias pre-filled)
//   else: conv1 tap t=(bid-896)/128, atomicAdd, colOff 512
// ---------------------------------------------------------------------------
__global__ __launch_bounds__(256) void gemm_multi(
    const u16* __restrict__ qbf, const u16* __restrict__ kbf, const u16* __restrict__ vbf,
    const u16* __restrict__ wqs, const u16* __restrict__ wvb,
    const u16* __restrict__ Wc0, const u16* __restrict__ Wc1,
    u16* __restrict__ Qp, u16* __restrict__ Vp, float* __restrict__ Kf32)
{
    __shared__ u16 As[128 * 32];
    __shared__ u16 Bs[128 * 32];
    int tid = threadIdx.x, lane = tid & 63, wave = tid >> 6;
    int waveM = (wave >> 1) * 64, waveN = (wave & 1) * 64;

    int bid = blockIdx.x;
    const u16 *A, *B;
    u16* Cst = nullptr;
    int rowOff, colOff = 0, strideB, mBase, nBase;
    bool isConv = false;
    if (bid < 256) {
        A = qbf; B = wqs; Cst = Qp; rowOff = 2; strideB = 1024;
        nBase = (bid & 7) * 128; mBase = (bid >> 3) * 128;
    } else if (bid < 512) {
        bid -= 256;
        A = vbf; B = wvb; Cst = Vp; rowOff = 2; strideB = 1024;
        nBase = (bid & 7) * 128; mBase = (bid >> 3) * 128;
    } else if (bid < 896) {
        int u = bid - 512, t = u >> 7, sub = u & 127;
        A = kbf; B = Wc0 + t * 1024; strideB = 3072; rowOff = 1 + t; isConv = true;
        nBase = (sub & 3) * 128; mBase = (sub >> 2) * 128;
    } else {
        int u = bid - 896, t = u >> 7, sub = u & 127;
        A = kbf; B = Wc1 + t * 1024; strideB = 5120; rowOff = t; colOff = 512; isConv = true;
        nBase = (sub & 3) * 128; mBase = (sub >> 2) * 128;
    }

    f32x4 acc[4][4];
    #pragma unroll
    for (int i = 0; i < 4; i++)
        #pragma unroll
        for (int j = 0; j < 4; j++) acc[i][j] = (f32x4){0.f, 0.f, 0.f, 0.f};

    for (int k0 = 0; k0 < 1024; k0 += 32) {
        __syncthreads();
        #pragma unroll
        for (int cc = 0; cc < 2; cc++) {
            int rbase = (wave * 2 + cc) * 16;
            int r = rbase + (lane >> 2);
            int gm = mBase + r;
            int grow = (gm >> 11) * SP + (gm & 2047) + rowOff;
            int csrc = (lane & 3) ^ (r & 3);
            gload16(A + (size_t)grow * 1024 + k0 + csrc * 8, &As[rbase * 32]);
            int gn = nBase + r;
            gload16(B + (size_t)gn * strideB + k0 + csrc * 8, &Bs[rbase * 32]);
        }
        __syncthreads();

        bf16x8 af[4], bfr[4];
        #pragma unroll
        for (int t = 0; t < 4; t++) {
            int mrow = waveM + t * 16 + (lane & 15);
            af[t] = *(const bf16x8*)&As[mrow * 32 + (((lane >> 4) ^ (mrow & 3))) * 8];
            int nrow = waveN + t * 16 + (lane & 15);
            bfr[t] = *(const bf16x8*)&Bs[nrow * 32 + (((lane >> 4) ^ (nrow & 3))) * 8];
        }
        #pragma unroll
        for (int mt = 0; mt < 4; mt++)
            #pragma unroll
            for (int nt = 0; nt < 4; nt++)
                acc[mt][nt] = __builtin_amdgcn_mfma_f32_16x16x32_bf16(
                    af[mt], bfr[nt], acc[mt][nt], 0, 0, 0);
    }

    #pragma unroll
    for (int mt = 0; mt < 4; mt++)
        #pragma unroll
        for (int nt = 0; nt < 4; nt++)
            #pragma unroll
            for (int r = 0; r < 4; r++) {
                int row = mBase + waveM + mt * 16 + (lane >> 4) * 4 + r;
                int gcol = nBase + waveN + nt * 16 + (lane & 15);
                if (isConv)
                    atomicAdd(&Kf32[(size_t)row * 1024 + colOff + gcol], acc[mt][nt][r]);
                else
                    Cst[(size_t)row * 1024 + gcol] = f2bf(acc[mt][nt][r]);
            }
}

// ---------------------------------------------------------------------------
// Keff fp32 -> bf16
// ---------------------------------------------------------------------------
__global__ void keff_convert(const float* __restrict__ Kf, u16* __restrict__ Keff)
{
    int idx = blockIdx.x * 256 + threadIdx.x;   // < NBSD/4
    int e = idx * 4;
    float4 v = *(const float4*)&Kf[e];
    u16x4 o;
    o[0] = f2bf(v.x); o[1] = f2bf(v.y); o[2] = f2bf(v.z); o[3] = f2bf(v.w);
    *(u16x4*)&Keff[e] = o;
}

// ---------------------------------------------------------------------------
// Out projection GEMM (fp32 out): out = AO @ wob^T + bo
// ---------------------------------------------------------------------------
__global__ __launch_bounds__(256) void gemm_out(
    const u16* __restrict__ A, const u16* __restrict__ Bw,
    float* __restrict__ Cf32, const float* __restrict__ bias)
{
    __shared__ u16 As[128 * 32];
    __shared__ u16 Bs[128 * 32];
    int tid = threadIdx.x, lane = tid & 63, wave = tid >> 6;
    int waveM = (wave >> 1) * 64, waveN = (wave & 1) * 64;
    int mBase = blockIdx.y * 128, nBase = blockIdx.x * 128;
    const int K = 1024;

    f32x4 acc[4][4];
    #pragma unroll
    for (int i = 0; i < 4; i++)
        #pragma unroll
        for (int j = 0; j < 4; j++) acc[i][j] = (f32x4){0.f, 0.f, 0.f, 0.f};

    for (int k0 = 0; k0 < K; k0 += 32) {
        __syncthreads();
        #pragma unroll
        for (int cc = 0; cc < 2; cc++) {
            int rbase = (wave * 2 + cc) * 16;
            int r = rbase + (lane >> 2);
            int gm = mBase + r;
            int grow = (gm >> 11) * SP + (gm & 2047) + 2;
            int csrc = (lane & 3) ^ (r & 3);
            gload16(A + (size_t)grow * 1024 + k0 + csrc * 8, &As[rbase * 32]);
            int gn = nBase + r;
            gload16(Bw + (size_t)gn * K + k0 + csrc * 8, &Bs[rbase * 32]);
        }
        __syncthreads();

        bf16x8 af[4], bfr[4];
        #pragma unroll
        for (int t = 0; t < 4; t++) {
            int mrow = waveM + t * 16 + (lane & 15);
            af[t] = *(const bf16x8*)&As[mrow * 32 + (((lane >> 4) ^ (mrow & 3))) * 8];
            int nrow = waveN + t * 16 + (lane & 15);
            bfr[t] = *(const bf16x8*)&Bs[nrow * 32 + (((lane >> 4) ^ (nrow & 3))) * 8];
        }
        #pragma unroll
        for (int mt = 0; mt < 4; mt++)
            #pragma unroll
            for (int nt = 0; nt < 4; nt++)
                acc[mt][nt] = __builtin_amdgcn_mfma_f32_16x16x32_bf16(
                    af[mt], bfr[nt], acc[mt][nt], 0, 0, 0);
    }

    #pragma unroll
    for (int mt = 0; mt < 4; mt++)
        #pragma unroll
        for (int nt = 0; nt < 4; nt++)
            #pragma unroll
            for (int r = 0; r < 4; r++) {
                int row = mBase + waveM + mt * 16 + (lane >> 4) * 4 + r;
                int gcol = nBase + waveN + nt * 16 + (lane & 15);
                Cf32[(size_t)row * 1024 + gcol] = acc[mt][nt][r] + bias[gcol];
            }
}

// ---------------------------------------------------------------------------
// Transpose Vp [B*S][1024] -> Vt [B][H][64][S] (bf16).
// ---------------------------------------------------------------------------
__global__ __launch_bounds__(256) void vtrans_kernel(const u16* __restrict__ Vp,
                                                     u16* __restrict__ Vt)
{
    __shared__ u16 t[64 * 64];
    int bid = blockIdx.x;
    int st = bid & 31, h = (bid >> 5) & 15, b = bid >> 9;
    int s0 = st * 64;
    int tid = threadIdx.x;
    #pragma unroll
    for (int w = 0; w < 2; w++) {
        int f = tid + w * 256;
        int row = f >> 3, c = f & 7;
        int p = c ^ (row & 7);
        u16x8 v = *(const u16x8*)&Vp[(size_t)(b * Ss + s0 + row) * Dd + h * 64 + c * 8];
        *(u16x8*)&t[row * 64 + p * 8] = v;
    }
    __syncthreads();
    #pragma unroll
    for (int w = 0; w < 2; w++) {
        int f = tid + w * 256;
        int d = f >> 3, s8 = (f & 7) * 8;
        u16x8 v;
        #pragma unroll
        for (int j = 0; j < 8; j++) {
            int s = s8 + j;
            v[j] = t[s * 64 + (((d >> 3) ^ (s & 7))) * 8 + (d & 7)];
        }
        *(u16x8*)&Vt[((size_t)(b * Hh + h) * 64 + d) * Ss + s0 + s8] = v;
    }
}

// ---------------------------------------------------------------------------
// bf16 MFMA flash attention — BARRIER-FREE:
// Q A-frags and K B-frags want 8 contiguous d-elements per lane, which the
// [s][d] global layout already provides -> load them DIRECTLY from global
// (16B dwordx4, L2-served), no LDS staging, no __syncthreads at all.
// (R6 post-mortem: the 2-barrier K-loop drained vmcnt(0) every tile;
// MfmaUtil 10%, VALUBusy 19% -> ~75% of cycles stalled at the barrier.)
// Only LDS use: wave-private P C-layout -> A-layout roundtrip (lgkm waits).
// ---------------------------------------------------------------------------
__global__ __launch_bounds__(256) void flash_kernel(
    const u16* __restrict__ Qp, const u16* __restrict__ Keff, const u16* __restrict__ Vt,
    const unsigned int* __restrict__ maskbits, const int* __restrict__ rowflags,
    u16* __restrict__ AO)
{
    __shared__ u16 Ps[4][16 * 64];
    int tid = threadIdx.x, lane = tid & 63, wave = tid >> 6;
    int q0 = blockIdx.x * 64, h = blockIdx.y, b = blockIdx.z;
    int quad = lane >> 4;

    int anyz = 0;
    #pragma unroll
    for (int r = 0; r < 4; r++)
        anyz |= rowflags[b * Ss + q0 + wave * 16 + quad * 4 + r];
    bool doMask = __any(anyz);

    float lrow[4] = {0.f, 0.f, 0.f, 0.f};
    f32x4 oa[4];
    #pragma unroll
    for (int nt = 0; nt < 4; nt++) oa[nt] = (f32x4){0.f, 0.f, 0.f, 0.f};

    // Q A-frags straight from global: row = q0 + wave*16 + (lane&15),
    // k-chunk c = ks*4+quad -> elements c*8..c*8+7 (contiguous in d).
    bf16x8 qa[2];
    {
        const u16* qrow = Qp + (size_t)(b * Ss + q0 + wave * 16 + (lane & 15)) * Dd + h * 64;
        #pragma unroll
        for (int ks = 0; ks < 2; ks++)
            qa[ks] = *(const bf16x8*)&qrow[(ks * 4 + quad) * 8];
    }

    const u16* vbase = Vt + (size_t)(b * Hh + h) * 64 * Ss;
    const u16* kbase = Keff + (size_t)b * Ss * Dd + h * 64;

    for (int k0 = 0; k0 < Ss; k0 += 64) {
        // K B-frags straight from global: row = k0 + nt*16 + (lane&15)
        bf16x8 kb[4][2];
        #pragma unroll
        for (int nt = 0; nt < 4; nt++) {
            const u16* krow = kbase + (size_t)(k0 + nt * 16 + (lane & 15)) * Dd;
            #pragma unroll
            for (int ks = 0; ks < 2; ks++)
                kb[nt][ks] = *(const bf16x8*)&krow[(ks * 4 + quad) * 8];
        }
        // V B-frags straight from global Vt
        bf16x8 vf[4][2];
        #pragma unroll
        for (int nt = 0; nt < 4; nt++)
            #pragma unroll
            for (int ks = 0; ks < 2; ks++) {
                int d = nt * 16 + (lane & 15);
                int kc = k0 + ks * 32 + quad * 8;
                vf[nt][ks] = *(const bf16x8*)&vbase[(size_t)d * Ss + kc];
            }

        // S = Q @ Keff^T (base-2 logits)
        f32x4 sa[4];
        #pragma unroll
        for (int nt = 0; nt < 4; nt++) sa[nt] = (f32x4){0.f, 0.f, 0.f, 0.f};
        #pragma unroll
        for (int nt = 0; nt < 4; nt++)
            #pragma unroll
            for (int ks = 0; ks < 2; ks++)
                sa[nt] = __builtin_amdgcn_mfma_f32_16x16x32_bf16(
                    qa[ks], kb[nt][ks], sa[nt], 0, 0, 0);

        if (doMask) {
            #pragma unroll
            for (int r = 0; r < 4; r++) {
                int qrow = q0 + wave * 16 + quad * 4 + r;
                const unsigned int* mb = &maskbits[((size_t)b * Ss + qrow) * 64 + (k0 >> 5)];
                unsigned int w0m = mb[0], w1m = mb[1];
                #pragma unroll
                for (int nt = 0; nt < 4; nt++) {
                    int col = nt * 16 + (lane & 15);
                    unsigned int w = (col & 32) ? w1m : w0m;
                    if (!((w >> (col & 31)) & 1u)) sa[nt][r] = -1.442695e9f;
                }
            }
        }

        // fixed-max softmax: p = 2^s; per-lane partial row-sum (no shuffles)
        #pragma unroll
        for (int r = 0; r < 4; r++) {
            float p0 = __builtin_amdgcn_exp2f(sa[0][r]);
            float p1 = __builtin_amdgcn_exp2f(sa[1][r]);
            float p2 = __builtin_amdgcn_exp2f(sa[2][r]);
            float p3 = __builtin_amdgcn_exp2f(sa[3][r]);
            sa[0][r] = p0; sa[1][r] = p1; sa[2][r] = p2; sa[3][r] = p3;
            lrow[r] += (p0 + p1) + (p2 + p3);
        }

        // P (C-layout) -> bf16 -> wave-private swizzled LDS (lgkm waits only)
        u16* pw = Ps[wave];
        #pragma unroll
        for (int nt = 0; nt < 4; nt++)
            #pragma unroll
            for (int r = 0; r < 4; r++) {
                int row = quad * 4 + r;
                int col = nt * 16 + (lane & 15);
                pw[row * 64 + (((col >> 3) ^ (row & 7))) * 8 + (col & 7)] =
                    f2bf(sa[nt][r]);
            }

        // O += P @ V
        bf16x8 pa[2];
        #pragma unroll
        for (int ks = 0; ks < 2; ks++) {
            int row = lane & 15;
            int c = ks * 4 + quad;
            pa[ks] = *(const bf16x8*)&pw[row * 64 + (c ^ (row & 7)) * 8];
        }
        #pragma unroll
        for (int nt = 0; nt < 4; nt++)
            #pragma unroll
            for (int ks = 0; ks < 2; ks++)
                oa[nt] = __builtin_amdgcn_mfma_f32_16x16x32_bf16(
                    pa[ks], vf[nt][ks], oa[nt], 0, 0, 0);
    }

    // epilogue: reduce l across the 16 lanes sharing each row; normalize; write
    #pragma unroll
    for (int r = 0; r < 4; r++) {
        float rs = lrow[r];
        #pragma unroll
        for (int d = 1; d < 16; d <<= 1) rs += __shfl_xor(rs, d, 64);
        float inv = 1.f / rs;
        int qrow = q0 + wave * 16 + quad * 4 + r;
        size_t rowbase = ((size_t)b * SP + 2 + qrow) * Dd + h * 64;
        #pragma unroll
        for (int nt = 0; nt < 4; nt++)
            AO[rowbase + nt * 16 + (lane & 15)] = f2bf(oa[nt][r] * inv);
    }
}

// ---------------------------------------------------------------------------
extern "C" void kernel_launch(void* const* d_in, const int* in_sizes, int n_in,
                              void* d_out, int out_size, void* d_ws, size_t ws_size,
                              hipStream_t stream)
{
    (void)in_sizes; (void)n_in; (void)out_size; (void)ws_size;
    const float* q    = (const float*)d_in[0];
    const float* k    = (const float*)d_in[1];
    const float* v    = (const float*)d_in[2];
    const int*   mask = (const int*)d_in[3];
    const float* Wq   = (const float*)d_in[4];
    const float* Wk   = (const float*)d_in[5];
    const float* Wv   = (const float*)d_in[6];
    const float* Wo   = (const float*)d_in[7];
    const float* bo   = (const float*)d_in[8];
    const float* w0   = (const float*)d_in[9];
    const float* b0   = (const float*)d_in[10];
    const float* w1   = (const float*)d_in[11];
    const float* b1   = (const float*)d_in[12];
    const float* gate = (const float*)d_in[13];
    float* out = (float*)d_out;

    char* p = (char*)d_ws;
    const size_t nPad = (size_t)Bb * SP * Dd;
    u16*   qbf  = (u16*)p;          p += nPad * 2;
    u16*   kbf  = (u16*)p;          p += nPad * 2;
    u16*   Vp   = (u16*)p;          p += (size_t)NBSD * 2;
    float* Kf32 = (float*)p;        p += (size_t)NBSD * 4;
    u16*   vbf  = (u16*)p;          p += nPad * 2;   // aliased as AO after V-GEMM
    u16*   Qp   = (u16*)p;          p += (size_t)NBSD * 2;
    u16*   Keff = (u16*)p;          p += (size_t)NBSD * 2;
    u16*   Vt   = (u16*)p;          p += (size_t)NBSD * 2;
    u16*   wqs  = (u16*)p;          p += (size_t)Dd * Dd * 2;
    u16*   wvb  = (u16*)p;          p += (size_t)Dd * Dd * 2;
    u16*   wob  = (u16*)p;          p += (size_t)Dd * Dd * 2;
    u16*   Wc0  = (u16*)p;          p += (size_t)512 * 3072 * 2;
    u16*   Wc1  = (u16*)p;          p += (size_t)512 * 5120 * 2;
    float* bc   = (float*)p;        p += 1024 * 4;
    unsigned int* mbits = (unsigned int*)p; p += (size_t)Bb * Ss * 64 * 4;
    int*   rflags = (int*)p;        p += (size_t)Bb * Ss * 4;
    u16*   AO   = vbf;

    {
        int total = 3 * 1024 * 1024 + 512 * 3072 + 512 * 5120 + 1024;
        hipLaunchKernelGGL(prep_weights, dim3((total + 255) / 256), dim3(256), 0, stream,
                           Wq, Wk, Wv, Wo, w0, b0, w1, b1, gate,
                           wqs, wvb, wob, Wc0, Wc1, bc);
    }
    {
        int total = 3 * (Bb * SP * Dd) / 8 + NBSD / 4;
        hipLaunchKernelGGL(convert_inputs, dim3((total + 255) / 256), dim3(256), 0, stream,
                           q, k, v, qbf, kbf, vbf, Kf32, bc);
    }
    hipLaunchKernelGGL(mask_prep, dim3(Bb * Ss), dim3(64), 0, stream, mask, mbits, rflags);

    // Q, V, conv0 taps x3, conv1 taps x5: 1536 uniform blocks
    hipLaunchKernelGGL(gemm_multi, dim3(1536), dim3(256), 0, stream,
                       qbf, kbf, vbf, wqs, wvb, Wc0, Wc1, Qp, Vp, Kf32);
    hipLaunchKernelGGL(keff_convert, dim3(NBSD / 4 / 256), dim3(256), 0, stream, Kf32, Keff);
    hipLaunchKernelGGL(vtrans_kernel, dim3(Bb * Hh * (Ss / 64)), dim3(256), 0, stream, Vp, Vt);
    hipLaunchKernelGGL(flash_kernel, dim3(Ss / 64, Hh, Bb), dim3(256), 0, stream,
                       Qp, Keff, Vt, mbits, rflags, AO);
    hipLaunchKernelGGL(gemm_out, dim3(8, 32), dim3(256), 0, stream,
                       AO, wob, out, bo);
}

// Round 8
// 436.765 us; speedup vs baseline: 1.3984x; 1.3984x over previous
//
#include <hip/hip_runtime.h>
#include <math.h>

#define Bb 2
#define Ss 2048
#define Dd 1024
#define Hh 16
#define SP 2052   // padded seq rows per batch (2 zero rows each side)
#define NBSD 4194304  // Bb*Ss*Dd

typedef unsigned short u16;
typedef __bf16 bf16x8 __attribute__((ext_vector_type(8)));
typedef float f32x4 __attribute__((ext_vector_type(4)));
typedef unsigned short u16x8 __attribute__((ext_vector_type(8)));
typedef unsigned short u16x4 __attribute__((ext_vector_type(4)));

__device__ __forceinline__ u16 f2bf(float f) {
    union { float f; unsigned int u; } c; c.f = f;
    unsigned int u = c.u + 0x7FFFu + ((c.u >> 16) & 1u);
    return (u16)(u >> 16);
}
__device__ __forceinline__ float bf2f(u16 b) {
    union { unsigned int u; float f; } c; c.u = ((unsigned int)b) << 16;
    return c.f;
}

__device__ __forceinline__ void gload16(const void* g, void* l) {
    __builtin_amdgcn_global_load_lds(
        (const __attribute__((address_space(1))) void*)g,
        (__attribute__((address_space(3))) void*)l, 16, 0, 0);
}

// ---------------------------------------------------------------------------
// Weight prep: bf16 conversions + gate/scale folding.
// ---------------------------------------------------------------------------
__global__ void prep_weights(const float* __restrict__ Wq, const float* __restrict__ Wk,
                             const float* __restrict__ Wv, const float* __restrict__ Wo,
                             const float* __restrict__ w0, const float* __restrict__ b0,
                             const float* __restrict__ w1, const float* __restrict__ b1,
                             const float* __restrict__ gate,
                             u16* __restrict__ wqs, u16* __restrict__ wvb, u16* __restrict__ wob,
                             u16* __restrict__ Wc0, u16* __restrict__ Wc1, float* __restrict__ bc)
{
    int idx = blockIdx.x * 256 + threadIdx.x;
    const int NW = 1024 * 1024;
    if (idx < NW) { wqs[idx] = f2bf(Wq[idx] * 0.18033688011112042f); return; }
    idx -= NW;
    if (idx < NW) { wvb[idx] = f2bf(Wv[idx]); return; }
    idx -= NW;
    if (idx < NW) { wob[idx] = f2bf(Wo[idx]); return; }
    idx -= NW;
    if (idx < 512 * 3072) {
        int c = idx / 3072, rem = idx % 3072, t = rem >> 10, d = rem & 1023;
        float g = 1.f / (1.f + expf(-gate[c >> 6]));
        float v = g * w0[(c * 1024 + d) * 3 + t];
        if (t == 1) v += (1.f - g) * Wk[c * 1024 + d];
        Wc0[idx] = f2bf(v);
        return;
    }
    idx -= 512 * 3072;
    if (idx < 512 * 5120) {
        int c = idx / 5120, rem = idx % 5120, t = rem >> 10, d = rem & 1023;
        int cg = c + 512;
        float g = 1.f / (1.f + expf(-gate[cg >> 6]));
        float v = g * w1[(c * 1024 + d) * 5 + t];
        if (t == 2) v += (1.f - g) * Wk[cg * 1024 + d];
        Wc1[idx] = f2bf(v);
        return;
    }
    idx -= 512 * 5120;
    if (idx < 1024) {
        float g = 1.f / (1.f + expf(-gate[idx >> 6]));
        bc[idx] = g * (idx < 512 ? b0[idx] : b1[idx - 512]);
    }
}

// ---------------------------------------------------------------------------
// fp32 -> bf16 conversion into padded [B][SP][D] layout.
// ---------------------------------------------------------------------------
__global__ void convert_inputs(const float* __restrict__ q, const float* __restrict__ k,
                               const float* __restrict__ v,
                               u16* __restrict__ qbf, u16* __restrict__ kbf, u16* __restrict__ vbf)
{
    int idx = blockIdx.x * 256 + threadIdx.x;
    const int per = (Bb * SP * Dd) / 8;    // 525312
    int which = idx / per;
    if (which >= 3) return;
    int e = (idx - which * per) * 8;
    const float* src = which == 0 ? q : which == 1 ? k : v;
    u16* dst = which == 0 ? qbf : which == 1 ? kbf : vbf;
    int rp = e >> 10, col = e & 1023;
    int b = rp / SP, r = rp - b * SP;
    u16x8 o;
    if (r >= 2 && r < SP - 2) {
        const float* s = &src[((size_t)b * Ss + (r - 2)) * Dd + col];
        float4 lo = *(const float4*)s, hi = *(const float4*)(s + 4);
        o[0] = f2bf(lo.x); o[1] = f2bf(lo.y); o[2] = f2bf(lo.z); o[3] = f2bf(lo.w);
        o[4] = f2bf(hi.x); o[5] = f2bf(hi.y); o[6] = f2bf(hi.z); o[7] = f2bf(hi.w);
    } else {
        #pragma unroll
        for (int j = 0; j < 8; j++) o[j] = 0;
    }
    *(u16x8*)&dst[e] = o;
}

// ---------------------------------------------------------------------------
// Mask compression: 32 int32 -> 1 bit word; per-row any-zero flag.
// ---------------------------------------------------------------------------
__global__ void mask_prep(const int* __restrict__ mask, unsigned int* __restrict__ bits,
                          int* __restrict__ rowflags)
{
    int row = blockIdx.x;
    int lane = threadIdx.x;
    const int* mp = mask + (size_t)row * Ss + lane * 32;
    unsigned int w = 0;
    #pragma unroll
    for (int j = 0; j < 32; j += 4) {
        int4 m4 = *(const int4*)&mp[j];
        if (m4.x != 0) w |= 1u << j;
        if (m4.y != 0) w |= 1u << (j + 1);
        if (m4.z != 0) w |= 1u << (j + 2);
        if (m4.w != 0) w |= 1u << (j + 3);
    }
    bits[(size_t)row * 64 + lane] = w;
    int anyz = __any(w != 0xFFFFFFFFu);
    if (lane == 0) rowflags[row] = anyz;
}

// ---------------------------------------------------------------------------
// Uniform bf16 MFMA GEMM, ALL blocks <=64 K-steps, NO atomics.
// conv branches split by taps into bf16 partial buffers (summed by
// keff_convert). 64-step blocks dispatched first for backfill balance.
//   bid<128:  c1A taps01 (64 steps)   -> p1a
//   <256:     c1B taps23 (64)         -> p1b
//   <384:     c0A taps01 (64)         -> p0a
//   <512:     c0B tap2   (32)         -> p0b
//   <640:     c1C tap4   (32)         -> p1c
//   <896:     Q   (32)                -> Qp
//   <1152:    V   (32)                -> Vp
// ---------------------------------------------------------------------------
__global__ __launch_bounds__(256) void gemm_multi(
    const u16* __restrict__ qbf, const u16* __restrict__ kbf, const u16* __restrict__ vbf,
    const u16* __restrict__ wqs, const u16* __restrict__ wvb,
    const u16* __restrict__ Wc0, const u16* __restrict__ Wc1,
    u16* __restrict__ Qp, u16* __restrict__ Vp,
    u16* __restrict__ p0a, u16* __restrict__ p0b,
    u16* __restrict__ p1a, u16* __restrict__ p1b, u16* __restrict__ p1c)
{
    __shared__ u16 As[128 * 32];
    __shared__ u16 Bs[128 * 32];
    int tid = threadIdx.x, lane = tid & 63, wave = tid >> 6;
    int waveM = (wave >> 1) * 64, waveN = (wave & 1) * 64;

    int bid = blockIdx.x;
    const u16 *A, *Bp;
    u16* Cst;
    int kLo, kHi, rowOff0, strideB, strideC, mBase, nBase;
    if (bid < 640) {   // conv blocks
        A = kbf; strideC = 512;
        int u, grp;
        if (bid < 128)      { grp = 0; u = bid; }
        else if (bid < 256) { grp = 1; u = bid - 128; }
        else if (bid < 384) { grp = 2; u = bid - 256; }
        else if (bid < 512) { grp = 3; u = bid - 384; }
        else                { grp = 4; u = bid - 512; }
        nBase = (u & 3) * 128; mBase = (u >> 2) * 128;
        switch (grp) {
            case 0: Bp = Wc1; Cst = p1a; kLo = 0;    kHi = 2048; rowOff0 = 0; strideB = 5120; break;
            case 1: Bp = Wc1; Cst = p1b; kLo = 2048; kHi = 4096; rowOff0 = 0; strideB = 5120; break;
            case 2: Bp = Wc0; Cst = p0a; kLo = 0;    kHi = 2048; rowOff0 = 1; strideB = 3072; break;
            case 3: Bp = Wc0; Cst = p0b; kLo = 2048; kHi = 3072; rowOff0 = 1; strideB = 3072; break;
            default:Bp = Wc1; Cst = p1c; kLo = 4096; kHi = 5120; rowOff0 = 0; strideB = 5120; break;
        }
    } else if (bid < 896) {  // Q
        int u = bid - 640;
        A = qbf; Bp = wqs; Cst = Qp; kLo = 0; kHi = 1024; rowOff0 = 2;
        strideB = 1024; strideC = 1024;
        nBase = (u & 7) * 128; mBase = (u >> 3) * 128;
    } else {                 // V
        int u = bid - 896;
        A = vbf; Bp = wvb; Cst = Vp; kLo = 0; kHi = 1024; rowOff0 = 2;
        strideB = 1024; strideC = 1024;
        nBase = (u & 7) * 128; mBase = (u >> 3) * 128;
    }

    f32x4 acc[4][4];
    #pragma unroll
    for (int i = 0; i < 4; i++)
        #pragma unroll
        for (int j = 0; j < 4; j++) acc[i][j] = (f32x4){0.f, 0.f, 0.f, 0.f};

    for (int k = kLo; k < kHi; k += 32) {
        __syncthreads();
        #pragma unroll
        for (int cc = 0; cc < 2; cc++) {
            int rbase = (wave * 2 + cc) * 16;
            int r = rbase + (lane >> 2);
            int gm = mBase + r;
            int grow = (gm >> 11) * SP + (gm & 2047) + rowOff0 + (k >> 10);
            int csrc = (lane & 3) ^ (r & 3);
            gload16(A + (size_t)grow * 1024 + (k & 1023) + csrc * 8, &As[rbase * 32]);
            int gn = nBase + r;
            gload16(Bp + (size_t)gn * strideB + k + csrc * 8, &Bs[rbase * 32]);
        }
        __syncthreads();

        bf16x8 af[4], bfr[4];
        #pragma unroll
        for (int t = 0; t < 4; t++) {
            int mrow = waveM + t * 16 + (lane & 15);
            af[t] = *(const bf16x8*)&As[mrow * 32 + (((lane >> 4) ^ (mrow & 3))) * 8];
            int nrow = waveN + t * 16 + (lane & 15);
            bfr[t] = *(const bf16x8*)&Bs[nrow * 32 + (((lane >> 4) ^ (nrow & 3))) * 8];
        }
        #pragma unroll
        for (int mt = 0; mt < 4; mt++)
            #pragma unroll
            for (int nt = 0; nt < 4; nt++)
                acc[mt][nt] = __builtin_amdgcn_mfma_f32_16x16x32_bf16(
                    af[mt], bfr[nt], acc[mt][nt], 0, 0, 0);
    }

    #pragma unroll
    for (int mt = 0; mt < 4; mt++)
        #pragma unroll
        for (int nt = 0; nt < 4; nt++)
            #pragma unroll
            for (int r = 0; r < 4; r++) {
                int row = mBase + waveM + mt * 16 + (lane >> 4) * 4 + r;
                int gcol = nBase + waveN + nt * 16 + (lane & 15);
                Cst[(size_t)row * strideC + gcol] = f2bf(acc[mt][nt][r]);
            }
}

// ---------------------------------------------------------------------------
// Keff assembly: sum bf16 conv partials + gated bias -> Keff bf16.
// ---------------------------------------------------------------------------
__global__ void keff_convert(const u16* __restrict__ p0a, const u16* __restrict__ p0b,
                             const u16* __restrict__ p1a, const u16* __restrict__ p1b,
                             const u16* __restrict__ p1c, const float* __restrict__ bc,
                             u16* __restrict__ Keff)
{
    int idx = blockIdx.x * 256 + threadIdx.x;   // < NBSD/4
    int e = idx * 4;
    int row = e >> 10, c = e & 1023;
    u16x4 o;
    if (c < 512) {
        size_t j = (size_t)row * 512 + c;
        u16x4 a = *(const u16x4*)&p0a[j], b = *(const u16x4*)&p0b[j];
        #pragma unroll
        for (int i = 0; i < 4; i++)
            o[i] = f2bf(bf2f(a[i]) + bf2f(b[i]) + bc[c + i]);
    } else {
        size_t j = (size_t)row * 512 + (c - 512);
        u16x4 a = *(const u16x4*)&p1a[j], b = *(const u16x4*)&p1b[j], d = *(const u16x4*)&p1c[j];
        #pragma unroll
        for (int i = 0; i < 4; i++)
            o[i] = f2bf(bf2f(a[i]) + bf2f(b[i]) + bf2f(d[i]) + bc[c + i]);
    }
    *(u16x4*)&Keff[(size_t)row * 1024 + c] = o;
}

// ---------------------------------------------------------------------------
// Out projection GEMM (fp32 out): out = AO @ wob^T + bo
// ---------------------------------------------------------------------------
__global__ __launch_bounds__(256) void gemm_out(
    const u16* __restrict__ A, const u16* __restrict__ Bw,
    float* __restrict__ Cf32, const float* __restrict__ bias)
{
    __shared__ u16 As[128 * 32];
    __shared__ u16 Bs[128 * 32];
    int tid = threadIdx.x, lane = tid & 63, wave = tid >> 6;
    int waveM = (wave >> 1) * 64, waveN = (wave & 1) * 64;
    int mBase = blockIdx.y * 128, nBase = blockIdx.x * 128;
    const int K = 1024;

    f32x4 acc[4][4];
    #pragma unroll
    for (int i = 0; i < 4; i++)
        #pragma unroll
        for (int j = 0; j < 4; j++) acc[i][j] = (f32x4){0.f, 0.f, 0.f, 0.f};

    for (int k0 = 0; k0 < K; k0 += 32) {
        __syncthreads();
        #pragma unroll
        for (int cc = 0; cc < 2; cc++) {
            int rbase = (wave * 2 + cc) * 16;
            int r = rbase + (lane >> 2);
            int gm = mBase + r;
            int grow = (gm >> 11) * SP + (gm & 2047) + 2;
            int csrc = (lane & 3) ^ (r & 3);
            gload16(A + (size_t)grow * 1024 + k0 + csrc * 8, &As[rbase * 32]);
            int gn = nBase + r;
            gload16(Bw + (size_t)gn * K + k0 + csrc * 8, &Bs[rbase * 32]);
        }
        __syncthreads();

        bf16x8 af[4], bfr[4];
        #pragma unroll
        for (int t = 0; t < 4; t++) {
            int mrow = waveM + t * 16 + (lane & 15);
            af[t] = *(const bf16x8*)&As[mrow * 32 + (((lane >> 4) ^ (mrow & 3))) * 8];
            int nrow = waveN + t * 16 + (lane & 15);
            bfr[t] = *(const bf16x8*)&Bs[nrow * 32 + (((lane >> 4) ^ (nrow & 3))) * 8];
        }
        #pragma unroll
        for (int mt = 0; mt < 4; mt++)
            #pragma unroll
            for (int nt = 0; nt < 4; nt++)
                acc[mt][nt] = __builtin_amdgcn_mfma_f32_16x16x32_bf16(
                    af[mt], bfr[nt], acc[mt][nt], 0, 0, 0);
    }

    #pragma unroll
    for (int mt = 0; mt < 4; mt++)
        #pragma unroll
        for (int nt = 0; nt < 4; nt++)
            #pragma unroll
            for (int r = 0; r < 4; r++) {
                int row = mBase + waveM + mt * 16 + (lane >> 4) * 4 + r;
                int gcol = nBase + waveN + nt * 16 + (lane & 15);
                Cf32[(size_t)row * 1024 + gcol] = acc[mt][nt][r] + bias[gcol];
            }
}

// ---------------------------------------------------------------------------
// Transpose Vp [B*S][1024] -> Vt [B][H][64][S] (bf16).
// ---------------------------------------------------------------------------
__global__ __launch_bounds__(256) void vtrans_kernel(const u16* __restrict__ Vp,
                                                     u16* __restrict__ Vt)
{
    __shared__ u16 t[64 * 64];
    int bid = blockIdx.x;
    int st = bid & 31, h = (bid >> 5) & 15, b = bid >> 9;
    int s0 = st * 64;
    int tid = threadIdx.x;
    #pragma unroll
    for (int w = 0; w < 2; w++) {
        int f = tid + w * 256;
        int row = f >> 3, c = f & 7;
        int p = c ^ (row & 7);
        u16x8 v = *(const u16x8*)&Vp[(size_t)(b * Ss + s0 + row) * Dd + h * 64 + c * 8];
        *(u16x8*)&t[row * 64 + p * 8] = v;
    }
    __syncthreads();
    #pragma unroll
    for (int w = 0; w < 2; w++) {
        int f = tid + w * 256;
        int d = f >> 3, s8 = (f & 7) * 8;
        u16x8 v;
        #pragma unroll
        for (int j = 0; j < 8; j++) {
            int s = s8 + j;
            v[j] = t[s * 64 + (((d >> 3) ^ (s & 7))) * 8 + (d & 7)];
        }
        *(u16x8*)&Vt[((size_t)(b * Hh + h) * 64 + d) * Ss + s0 + s8] = v;
    }
}

// ---------------------------------------------------------------------------
// bf16 MFMA flash attention: 64-row Q-tiles, DOUBLE-BUFFERED K staging,
// cross-iteration V prefetch. One barrier per k-tile; the staging +
// V-loads for tile t+1 are issued right after tile t's QK MFMAs, so the
// barrier drain at the iteration end overlaps ~350 cycles of softmax/PV.
// (R7 post-mortem: direct per-lane global K frags serialized at VGPR=68;
// batched global_load_lds staging restored, now pipelined.)
// ---------------------------------------------------------------------------
__global__ __launch_bounds__(256, 3) void flash_kernel(
    const u16* __restrict__ Qp, const u16* __restrict__ Keff, const u16* __restrict__ Vt,
    const unsigned int* __restrict__ maskbits, const int* __restrict__ rowflags,
    u16* __restrict__ AO)
{
    __shared__ u16 Qs[64 * 64];
    __shared__ u16 Ks[2][64 * 64];
    __shared__ u16 Ps[4][16 * 64];
    int tid = threadIdx.x, lane = tid & 63, wave = tid >> 6;
    int q0 = blockIdx.x * 64, h = blockIdx.y, b = blockIdx.z;
    int quad = lane >> 4;

    // stage Q (8 chunks of 8 rows) and K tile 0 into Ks[0]
    #pragma unroll
    for (int cc = 0; cc < 2; cc++) {
        int rbase = (wave * 2 + cc) * 8;
        int r = rbase + (lane >> 3);
        int csrc = (lane & 7) ^ (r & 7);
        gload16(Qp + (size_t)(b * Ss + q0 + r) * Dd + h * 64 + csrc * 8, &Qs[rbase * 64]);
        gload16(Keff + (size_t)(b * Ss + r) * Dd + h * 64 + csrc * 8, &Ks[0][rbase * 64]);
    }

    int anyz = 0;
    #pragma unroll
    for (int r = 0; r < 4; r++)
        anyz |= rowflags[b * Ss + q0 + wave * 16 + quad * 4 + r];
    bool doMask = __any(anyz);

    const u16* vbase = Vt + (size_t)(b * Hh + h) * 64 * Ss;

    // preload V frags for tile 0 (registers)
    bf16x8 vfc[4][2];
    #pragma unroll
    for (int nt = 0; nt < 4; nt++)
        #pragma unroll
        for (int ks = 0; ks < 2; ks++) {
            int d = nt * 16 + (lane & 15);
            vfc[nt][ks] = *(const bf16x8*)&vbase[(size_t)d * Ss + ks * 32 + quad * 8];
        }

    float lrow[4] = {0.f, 0.f, 0.f, 0.f};
    f32x4 oa[4];
    #pragma unroll
    for (int nt = 0; nt < 4; nt++) oa[nt] = (f32x4){0.f, 0.f, 0.f, 0.f};

    __syncthreads();   // Q + K0 staged (also drains V preload issue)

    // Q A-frags are loop-invariant: hoist
    bf16x8 qa[2];
    #pragma unroll
    for (int ks = 0; ks < 2; ks++) {
        int mr = wave * 16 + (lane & 15);
        int c = ks * 4 + quad;
        qa[ks] = *(const bf16x8*)&Qs[mr * 64 + (c ^ (mr & 7)) * 8];
    }

    for (int it = 0; it < Ss / 64; ++it) {
        int k0 = it * 64;
        int p = it & 1;

        // S = Q @ Keff^T from Ks[p]
        f32x4 sa[4];
        #pragma unroll
        for (int nt = 0; nt < 4; nt++) sa[nt] = (f32x4){0.f, 0.f, 0.f, 0.f};
        bf16x8 kb[4][2];
        #pragma unroll
        for (int nt = 0; nt < 4; nt++)
            #pragma unroll
            for (int ks = 0; ks < 2; ks++) {
                int nr = nt * 16 + (lane & 15);
                int c = ks * 4 + quad;
                kb[nt][ks] = *(const bf16x8*)&Ks[p][nr * 64 + (c ^ (nr & 7)) * 8];
            }
        #pragma unroll
        for (int nt = 0; nt < 4; nt++)
            #pragma unroll
            for (int ks = 0; ks < 2; ks++)
                sa[nt] = __builtin_amdgcn_mfma_f32_16x16x32_bf16(
                    qa[ks], kb[nt][ks], sa[nt], 0, 0, 0);

        // issue NEXT tile's K staging + V frag loads now (overlaps softmax/PV;
        // loads cannot sink past the s_barrier below)
        bf16x8 vfn[4][2];
        if (it + 1 < Ss / 64) {
            int k1 = k0 + 64;
            #pragma unroll
            for (int cc = 0; cc < 2; cc++) {
                int rbase = (wave * 2 + cc) * 8;
                int r = rbase + (lane >> 3);
                int csrc = (lane & 7) ^ (r & 7);
                gload16(Keff + (size_t)(b * Ss + k1 + r) * Dd + h * 64 + csrc * 8,
                        &Ks[p ^ 1][rbase * 64]);
            }
            #pragma unroll
            for (int nt = 0; nt < 4; nt++)
                #pragma unroll
                for (int ks = 0; ks < 2; ks++) {
                    int d = nt * 16 + (lane & 15);
                    vfn[nt][ks] = *(const bf16x8*)&vbase[(size_t)d * Ss + k1 + ks * 32 + quad * 8];
                }
        }

        if (doMask) {
            #pragma unroll
            for (int r = 0; r < 4; r++) {
                int qrow = q0 + wave * 16 + quad * 4 + r;
                const unsigned int* mb = &maskbits[((size_t)b * Ss + qrow) * 64 + (k0 >> 5)];
                unsigned int w0m = mb[0], w1m = mb[1];
                #pragma unroll
                for (int nt = 0; nt < 4; nt++) {
                    int col = nt * 16 + (lane & 15);
                    unsigned int w = (col & 32) ? w1m : w0m;
                    if (!((w >> (col & 31)) & 1u)) sa[nt][r] = -1.442695e9f;
                }
            }
        }

        // fixed-max softmax: p = 2^s; per-lane partial row-sum
        #pragma unroll
        for (int r = 0; r < 4; r++) {
            float e0 = __builtin_amdgcn_exp2f(sa[0][r]);
            float e1 = __builtin_amdgcn_exp2f(sa[1][r]);
            float e2 = __builtin_amdgcn_exp2f(sa[2][r]);
            float e3 = __builtin_amdgcn_exp2f(sa[3][r]);
            sa[0][r] = e0; sa[1][r] = e1; sa[2][r] = e2; sa[3][r] = e3;
            lrow[r] += (e0 + e1) + (e2 + e3);
        }

        // P (C-layout) -> bf16 -> wave-private swizzled LDS
        u16* pw = Ps[wave];
        #pragma unroll
        for (int nt = 0; nt < 4; nt++)
            #pragma unroll
            for (int r = 0; r < 4; r++) {
                int row = quad * 4 + r;
                int col = nt * 16 + (lane & 15);
                pw[row * 64 + (((col >> 3) ^ (row & 7))) * 8 + (col & 7)] =
                    f2bf(sa[nt][r]);
            }

        // O += P @ V (vfc in registers)
        bf16x8 pa[2];
        #pragma unroll
        for (int ks = 0; ks < 2; ks++) {
            int row = lane & 15;
            int c = ks * 4 + quad;
            pa[ks] = *(const bf16x8*)&pw[row * 64 + (c ^ (row & 7)) * 8];
        }
        #pragma unroll
        for (int nt = 0; nt < 4; nt++)
            #pragma unroll
            for (int ks = 0; ks < 2; ks++)
                oa[nt] = __builtin_amdgcn_mfma_f32_16x16x32_bf16(
                    pa[ks], vfc[nt][ks], oa[nt], 0, 0, 0);

        // rotate V frags
        #pragma unroll
        for (int nt = 0; nt < 4; nt++)
            #pragma unroll
            for (int ks = 0; ks < 2; ks++)
                vfc[nt][ks] = vfn[nt][ks];

        __syncthreads();   // Ks[p^1] staged; all waves done reading Ks[p]
    }

    // epilogue: reduce l across the 16 lanes sharing each row; normalize; write
    #pragma unroll
    for (int r = 0; r < 4; r++) {
        float rs = lrow[r];
        #pragma unroll
        for (int d = 1; d < 16; d <<= 1) rs += __shfl_xor(rs, d, 64);
        float inv = 1.f / rs;
        int qrow = q0 + wave * 16 + quad * 4 + r;
        size_t rowbase = ((size_t)b * SP + 2 + qrow) * Dd + h * 64;
        #pragma unroll
        for (int nt = 0; nt < 4; nt++)
            AO[rowbase + nt * 16 + (lane & 15)] = f2bf(oa[nt][r] * inv);
    }
}

// ---------------------------------------------------------------------------
extern "C" void kernel_launch(void* const* d_in, const int* in_sizes, int n_in,
                              void* d_out, int out_size, void* d_ws, size_t ws_size,
                              hipStream_t stream)
{
    (void)in_sizes; (void)n_in; (void)out_size; (void)ws_size;
    const float* q    = (const float*)d_in[0];
    const float* k    = (const float*)d_in[1];
    const float* v    = (const float*)d_in[2];
    const int*   mask = (const int*)d_in[3];
    const float* Wq   = (const float*)d_in[4];
    const float* Wk   = (const float*)d_in[5];
    const float* Wv   = (const float*)d_in[6];
    const float* Wo   = (const float*)d_in[7];
    const float* bo   = (const float*)d_in[8];
    const float* w0   = (const float*)d_in[9];
    const float* b0   = (const float*)d_in[10];
    const float* w1   = (const float*)d_in[11];
    const float* b1   = (const float*)d_in[12];
    const float* gate = (const float*)d_in[13];
    float* out = (float*)d_out;

    char* p = (char*)d_ws;
    const size_t nPad = (size_t)Bb * SP * Dd;
    const size_t nHalf = (size_t)Bb * Ss * 512;   // partial buffer elems
    u16*   qbf  = (u16*)p;          p += nPad * 2;
    u16*   kbf  = (u16*)p;          p += nPad * 2;
    u16*   Vp   = (u16*)p;          p += (size_t)NBSD * 2;
    u16*   p0a  = (u16*)p;          p += nHalf * 2;
    u16*   p0b  = (u16*)p;          p += nHalf * 2;
    u16*   p1a  = (u16*)p;          p += nHalf * 2;
    u16*   p1b  = (u16*)p;          p += nHalf * 2;
    u16*   p1c  = (u16*)p;          p += nHalf * 2;
    u16*   vbf  = (u16*)p;          p += nPad * 2;   // aliased as AO after V-GEMM
    u16*   Qp   = (u16*)p;          p += (size_t)NBSD * 2;
    u16*   Keff = (u16*)p;          p += (size_t)NBSD * 2;
    u16*   Vt   = (u16*)p;          p += (size_t)NBSD * 2;
    u16*   wqs  = (u16*)p;          p += (size_t)Dd * Dd * 2;
    u16*   wvb  = (u16*)p;          p += (size_t)Dd * Dd * 2;
    u16*   wob  = (u16*)p;          p += (size_t)Dd * Dd * 2;
    u16*   Wc0  = (u16*)p;          p += (size_t)512 * 3072 * 2;
    u16*   Wc1  = (u16*)p;          p += (size_t)512 * 5120 * 2;
    float* bc   = (float*)p;        p += 1024 * 4;
    unsigned int* mbits = (unsigned int*)p; p += (size_t)Bb * Ss * 64 * 4;
    int*   rflags = (int*)p;        p += (size_t)Bb * Ss * 4;
    u16*   AO   = vbf;

    {
        int total = 3 * 1024 * 1024 + 512 * 3072 + 512 * 5120 + 1024;
        hipLaunchKernelGGL(prep_weights, dim3((total + 255) / 256), dim3(256), 0, stream,
                           Wq, Wk, Wv, Wo, w0, b0, w1, b1, gate,
                           wqs, wvb, wob, Wc0, Wc1, bc);
    }
    {
        int total = 3 * (Bb * SP * Dd) / 8;
        hipLaunchKernelGGL(convert_inputs, dim3((total + 255) / 256), dim3(256), 0, stream,
                           q, k, v, qbf, kbf, vbf);
    }
    hipLaunchKernelGGL(mask_prep, dim3(Bb * Ss), dim3(64), 0, stream, mask, mbits, rflags);

    // 1152 uniform blocks (<=64 K-steps each), long blocks first
    hipLaunchKernelGGL(gemm_multi, dim3(1152), dim3(256), 0, stream,
                       qbf, kbf, vbf, wqs, wvb, Wc0, Wc1, Qp, Vp,
                       p0a, p0b, p1a, p1b, p1c);
    hipLaunchKernelGGL(keff_convert, dim3(NBSD / 4 / 256), dim3(256), 0, stream,
                       p0a, p0b, p1a, p1b, p1c, bc, Keff);
    hipLaunchKernelGGL(vtrans_kernel, dim3(Bb * Hh * (Ss / 64)), dim3(256), 0, stream, Vp, Vt);
    hipLaunchKernelGGL(flash_kernel, dim3(Ss / 64, Hh, Bb), dim3(256), 0, stream,
                       Qp, Keff, Vt, mbits, rflags, AO);
    hipLaunchKernelGGL(gemm_out, dim3(8, 32), dim3(256), 0, stream,
                       AO, wob, out, bo);
}